// Round 7
// baseline (123.913 us; speedup 1.0000x reference)
//
#include <hip/hip_runtime.h>
#include <hip/hip_fp16.h>
#include <cstdint>
#include <cstddef>

// FastGRNN cell, MI355X fp16-MFMA, v7.
// prep:   weights f32->f16 into wb.
// stage1: G K-split panels, NO LDS / NO BARRIERS — direct global->register MFMA
//         fragment loads (A f32 cvt in reg, B f16 native). rb12[8192][G*256].
// reduce: rb12 -> rb2[8192][512] f16 (fixed-order panel sums; deterministic).
// stage2: pre = rb2 @ [W2|U2]^T (K=512) + fused sigmoid/tanh epilogue.

typedef _Float16 half8 __attribute__((ext_vector_type(8)));
typedef float f32x4 __attribute__((ext_vector_type(4)));

#define DIN 1024
#define DH 2048
#define RK 256
// wb half-offsets
#define OFF_W1H 0
#define OFF_U1H 262144
#define OFF_W2H 786432
#define OFF_U2H 1310720
#define WB_HALVES 1835008

__device__ __forceinline__ half8 cvt8(const float4 a, const float4 b) {
  half8 h;
  h[0] = (_Float16)a.x; h[1] = (_Float16)a.y; h[2] = (_Float16)a.z; h[3] = (_Float16)a.w;
  h[4] = (_Float16)b.x; h[5] = (_Float16)b.y; h[6] = (_Float16)b.z; h[7] = (_Float16)b.w;
  return h;
}

// ---------------- prep: weights f32 -> f16 ----------------------------------
__global__ __launch_bounds__(256)
void fgrnn_prep(const float* __restrict__ W1, const float* __restrict__ U1,
                const float* __restrict__ W2, const float* __restrict__ U2,
                _Float16* __restrict__ wb) {
  const int q = blockIdx.x * 256 + threadIdx.x;
  const float* src;
  int rel;
  if (q < 65536) { src = W1; rel = q; }
  else if (q < 196608) { src = U1; rel = q - 65536; }
  else if (q < 327680) { src = W2; rel = q - 196608; }
  else { src = U2; rel = q - 327680; }
  const float4 v = reinterpret_cast<const float4*>(src)[rel];
  union { _Float16 h[4]; uint2 u; } cv;
  cv.h[0] = (_Float16)v.x; cv.h[1] = (_Float16)v.y;
  cv.h[2] = (_Float16)v.z; cv.h[3] = (_Float16)v.w;
  reinterpret_cast<uint2*>(wb)[q] = cv.u;
}

// ---------------- stage 1: direct-from-global MFMA, no LDS ------------------
// G*64 blocks x 512 threads; 8 waves 2x4, wave tile 64x64 (acc[4][4]).
// Lane frag addressing (16x16x32): A row = (lane&15)+16*mi, k = 8*(lane>>4)+kk.
// Fully unrolled load+MFMA stream; compiler pipelines (no barriers to drain).
template <int G>
__global__ __launch_bounds__(512, 3)
void fgrnn_stage1(const float* __restrict__ x, const float* __restrict__ h,
                  const _Float16* __restrict__ wb, _Float16* __restrict__ rb12) {
  constexpr int KL = (G == 6) ? 512 : 256;   // K per panel
  constexpr int STEPS = KL / 32;             // K-chunks of 32
  constexpr int GX = 1024 / KL;              // x panels
  constexpr int RBLD = G * 256;
  constexpr int NB = G * 64;

  const int bid = blockIdx.x;
  const int L = (bid & 7) * (NB / 8) + (bid >> 3);  // XCD chunk swizzle
  const int g = L >> 6;
  const int mtile = L & 63;
  const bool isx = g < GX;
  const float* A = isx ? x : h;
  const int KA = isx ? DIN : DH;
  const int kbase = (isx ? g : (g - GX)) * KL;
  const _Float16* Bw = wb + (isx ? OFF_U1H : OFF_W1H);  // fixed below
  const _Float16* Bw2 = wb + (isx ? OFF_W1H : OFF_U1H);
  (void)Bw;
  const int row0 = mtile * 128;
  const int colbase = g * 256;

  const int tid = threadIdx.x;
  const int lane = tid & 63;
  const int w = tid >> 6;
  const int wr = w >> 2, wc = w & 3;

  const int klane = 8 * (lane >> 4);
  const int arow = row0 + wr * 64 + (lane & 15);
  const int brow = wc * 64 + (lane & 15);
  const float* Abase = A + (size_t)arow * KA + kbase + klane;
  const _Float16* Bbase = Bw2 + (size_t)brow * KA + kbase + klane;

  f32x4 acc[4][4];
#pragma unroll
  for (int i = 0; i < 4; ++i)
#pragma unroll
    for (int j = 0; j < 4; ++j) acc[i][j] = (f32x4){0.f, 0.f, 0.f, 0.f};

#pragma unroll
  for (int s = 0; s < STEPS; ++s) {
    const int ko = s * 32;
    float4 a0[4], a1[4];
    half8 bf[4];
#pragma unroll
    for (int mi = 0; mi < 4; ++mi) {
      const float* p = Abase + (size_t)(mi * 16) * KA + ko;
      a0[mi] = *reinterpret_cast<const float4*>(p);
      a1[mi] = *reinterpret_cast<const float4*>(p + 4);
    }
#pragma unroll
    for (int ni = 0; ni < 4; ++ni)
      bf[ni] = *reinterpret_cast<const half8*>(Bbase + (size_t)(ni * 16) * KA + ko);
    half8 af[4];
#pragma unroll
    for (int mi = 0; mi < 4; ++mi) af[mi] = cvt8(a0[mi], a1[mi]);
#pragma unroll
    for (int mi = 0; mi < 4; ++mi)
#pragma unroll
      for (int ni = 0; ni < 4; ++ni)
        acc[mi][ni] =
            __builtin_amdgcn_mfma_f32_16x16x32_f16(af[mi], bf[ni], acc[mi][ni], 0, 0, 0);
  }

  // D layout (16x16 family): row = 4*(lane>>4)+e, col = lane&15.
#pragma unroll
  for (int mi = 0; mi < 4; ++mi)
#pragma unroll
    for (int ni = 0; ni < 4; ++ni)
#pragma unroll
      for (int e = 0; e < 4; ++e) {
        const int row = row0 + wr * 64 + mi * 16 + 4 * (lane >> 4) + e;
        const int col = colbase + wc * 64 + ni * 16 + (lane & 15);
        rb12[(size_t)row * RBLD + col] = (_Float16)acc[mi][ni][e];
      }
}

// ---------------- reduce: rb12[8192][G*256] -> rb2[8192][512] ---------------
template <int G>
__global__ __launch_bounds__(256)
void fgrnn_reduce(const _Float16* __restrict__ rb12, _Float16* __restrict__ rb2) {
  constexpr int GX = (G == 6) ? 2 : 4;
  constexpr int GH = G - GX;
  constexpr int RBLD = G * 256;
  const int t = blockIdx.x * 256 + threadIdx.x;  // 0..524287
  const int row = t >> 6;
  const int ch = t & 63;
  const _Float16* src = rb12 + (size_t)row * RBLD;
  half8 s;
  int outcol;
  if (ch < 32) {
    const int c = ch * 8;
    s = *reinterpret_cast<const half8*>(src + c);
#pragma unroll
    for (int g = 1; g < GX; ++g)
      s = s + *reinterpret_cast<const half8*>(src + g * 256 + c);
    outcol = c;
  } else {
    const int c = (ch - 32) * 8;
    const _Float16* su = src + GX * 256;
    s = *reinterpret_cast<const half8*>(su + c);
#pragma unroll
    for (int g = 1; g < GH; ++g)
      s = s + *reinterpret_cast<const half8*>(su + g * 256 + c);
    outcol = 256 + c;
  }
  *reinterpret_cast<half8*>(rb2 + (size_t)row * 512 + outcol) = s;
}

// ---------------- stage 2: pre = rb2 @ [W2|U2]^T, K=512 ---------------------
// 2048 blocks x 256 threads. BM=64, BN=128, BK=64, 8 iters; 4 waves 2x2,
// wave tile 32x64 (acc[2][4]). Pure f16 copies on both staging paths.
__global__ __launch_bounds__(256)
void fgrnn_stage2(const _Float16* __restrict__ rb2, const _Float16* __restrict__ wb,
                  const float* __restrict__ state,
                  const float* __restrict__ bg, const float* __restrict__ bu,
                  const float* __restrict__ zeta, const float* __restrict__ nu,
                  float* __restrict__ out) {
  const int bid = blockIdx.x;
  const int L = (bid & 7) * 256 + (bid >> 3);   // XCD swizzle: mtile-banded
  const int mtile = L >> 4;   // 0..127
  const int ntile = L & 15;   // 0..15
  const int row0 = mtile * 64;
  const int col0 = ntile * 128;
  const _Float16* W2h = wb + OFF_W2H;
  const _Float16* U2h = wb + OFF_U2H;

  __shared__ _Float16 As[64 * 64];
  __shared__ _Float16 Bs[128 * 64];

  const int tid = threadIdx.x;
  const int lane = tid & 63;
  const int w = tid >> 6;
  const int wr = w >> 1, wc = w & 1;

  f32x4 acc[2][4];
#pragma unroll
  for (int i = 0; i < 2; ++i)
#pragma unroll
    for (int j = 0; j < 4; ++j) acc[i][j] = (f32x4){0.f, 0.f, 0.f, 0.f};

  const int sr = tid >> 3;      // 0..31
  const int sc = (tid & 7) * 8;

  half8 pa[2], pb[4];

  auto LOADG = [&](int it) {
    const int k0 = it * 64;
#pragma unroll
    for (int j = 0; j < 2; ++j)
      pa[j] = *reinterpret_cast<const half8*>(rb2 + (size_t)(row0 + j * 32 + sr) * 512 + k0 + sc);
    const _Float16* Bh = (k0 < 256) ? W2h : U2h;
    const int kb = k0 & 255;
#pragma unroll
    for (int j = 0; j < 4; ++j)
      pb[j] = *reinterpret_cast<const half8*>(Bh + (size_t)(col0 + j * 32 + sr) * RK + kb + sc);
  };
  auto STORE = [&]() {
#pragma unroll
    for (int j = 0; j < 2; ++j) {
      const int r = j * 32 + sr;
      *reinterpret_cast<half8*>(&As[r * 64 + (sc ^ ((r & 7) << 3))]) = pa[j];
    }
#pragma unroll
    for (int j = 0; j < 4; ++j) {
      const int r = j * 32 + sr;
      *reinterpret_cast<half8*>(&Bs[r * 64 + (sc ^ ((r & 7) << 3))]) = pb[j];
    }
  };

  LOADG(0);
  STORE();
  __syncthreads();

  for (int it = 0; it < 8; ++it) {
    const bool more = (it + 1 < 8);
    if (more) LOADG(it + 1);
#pragma unroll
    for (int kk = 0; kk < 64; kk += 32) {
      half8 af[2], bf[4];
#pragma unroll
      for (int mi = 0; mi < 2; ++mi) {
        const int r = wr * 32 + mi * 16 + (lane & 15);
        af[mi] = *reinterpret_cast<const half8*>(
            &As[r * 64 + ((kk + 8 * (lane >> 4)) ^ ((r & 7) << 3))]);
      }
#pragma unroll
      for (int ni = 0; ni < 4; ++ni) {
        const int r = wc * 64 + ni * 16 + (lane & 15);
        bf[ni] = *reinterpret_cast<const half8*>(
            &Bs[r * 64 + ((kk + 8 * (lane >> 4)) ^ ((r & 7) << 3))]);
      }
#pragma unroll
      for (int mi = 0; mi < 2; ++mi)
#pragma unroll
        for (int ni = 0; ni < 4; ++ni)
          acc[mi][ni] =
              __builtin_amdgcn_mfma_f32_16x16x32_f16(af[mi], bf[ni], acc[mi][ni], 0, 0, 0);
    }
    if (more) {
      __syncthreads();
      STORE();
    }
    __syncthreads();
  }

  // Fused epilogue (fast exp2/rcp; asymptotes correct)
  const float LOG2E = 1.44269504f;
  const float sz = __builtin_amdgcn_rcpf(1.f + __builtin_amdgcn_exp2f(-zeta[0] * LOG2E));
  const float sn = __builtin_amdgcn_rcpf(1.f + __builtin_amdgcn_exp2f(-nu[0] * LOG2E));
#pragma unroll
  for (int mi = 0; mi < 2; ++mi)
#pragma unroll
    for (int ni = 0; ni < 4; ++ni) {
      const int col = col0 + wc * 64 + ni * 16 + (lane & 15);
      const float bgc = bg[col];
      const float buc = bu[col];
#pragma unroll
      for (int e = 0; e < 4; ++e) {
        const int row = row0 + wr * 32 + mi * 16 + 4 * (lane >> 4) + e;
        const float pre = acc[mi][ni][e];
        const float zg =
            __builtin_amdgcn_rcpf(1.f + __builtin_amdgcn_exp2f(-(pre + bgc) * LOG2E));
        const float hc =
            1.f - 2.f * __builtin_amdgcn_rcpf(
                            1.f + __builtin_amdgcn_exp2f((pre + buc) * (2.f * LOG2E)));
        const float sv = state[(size_t)row * DH + col];
        out[(size_t)row * DH + col] = zg * sv + (sz * (1.f - zg) + sn) * hc;
      }
    }
}

extern "C" void kernel_launch(void* const* d_in, const int* in_sizes, int n_in,
                              void* d_out, int out_size, void* d_ws, size_t ws_size,
                              hipStream_t stream) {
  const float* input = (const float*)d_in[0];
  const float* state = (const float*)d_in[1];
  const float* W1 = (const float*)d_in[2];
  const float* W2 = (const float*)d_in[3];
  const float* U1 = (const float*)d_in[4];
  const float* U2 = (const float*)d_in[5];
  const float* bg = (const float*)d_in[6];
  const float* bu = (const float*)d_in[7];
  const float* zeta = (const float*)d_in[8];
  const float* nu = (const float*)d_in[9];
  float* out = (float*)d_out;

  _Float16* base = (_Float16*)d_ws;
  const size_t need12 = ((size_t)8192 * 3072 + (size_t)8192 * 512 + WB_HALVES) * 2;

  if (ws_size >= need12) {
    _Float16* rb12 = base;                              // 50.3 MB
    _Float16* rb2 = rb12 + (size_t)8192 * 3072;         // 8.4 MB
    _Float16* wb = rb2 + (size_t)8192 * 512;            // 3.67 MB
    fgrnn_prep<<<1792, 256, 0, stream>>>(W1, U1, W2, U2, wb);
    fgrnn_stage1<12><<<768, 512, 0, stream>>>(input, state, wb, rb12);
    fgrnn_reduce<12><<<2048, 256, 0, stream>>>(rb12, rb2);
    fgrnn_stage2<<<2048, 256, 0, stream>>>(rb2, wb, state, bg, bu, zeta, nu, out);
  } else {
    _Float16* rb12 = base;                              // 25.2 MB (G=6)
    _Float16* rb2 = rb12 + (size_t)8192 * 1536;
    _Float16* wb = rb2 + (size_t)8192 * 512;
    fgrnn_prep<<<1792, 256, 0, stream>>>(W1, U1, W2, U2, wb);
    fgrnn_stage1<6><<<384, 512, 0, stream>>>(input, state, wb, rb12);
    fgrnn_reduce<6><<<2048, 256, 0, stream>>>(rb12, rb2);
    fgrnn_stage2<<<2048, 256, 0, stream>>>(rb2, wb, state, bg, bu, zeta, nu, out);
  }
}

// Round 8
// 69.028 us; speedup vs baseline: 1.7951x; 1.7951x over previous
//
#include <hip/hip_runtime.h>
#include <hip/hip_fp16.h>
#include <cstdint>
#include <cstddef>

// FastGRNN cell, MI355X fp16-MFMA, v8.
// prep:   weights f32->f16 into wb.
// stage1: 256 blocks (exactly 1/CU, single round): bid<128 -> x@W1^T (BM=64),
//         128..191 -> h@U1^T k<1024 (BM=128), 192..255 -> h@U1^T k>=1024.
//         Double-buffered LDS, raw s_barrier + lgkmcnt-only waits (global loads
//         for tile t+2 stay in flight across barriers). rbuf[8192][768] f16.
// stage2: pre = [wx | uh0+uh1] @ [W2|U2]^T (K=512), fused sigmoid/tanh epilogue.

typedef _Float16 half8 __attribute__((ext_vector_type(8)));
typedef float f32x4 __attribute__((ext_vector_type(4)));

#define DIN 1024
#define DH 2048
#define RK 256
#define RBLD 768
// wb half-offsets
#define OFF_W1H 0
#define OFF_U1H 262144
#define OFF_W2H 786432
#define OFF_U2H 1310720
#define WB_HALVES 1835008

__device__ __forceinline__ half8 cvt8(const float4 a, const float4 b) {
  half8 h;
  h[0] = (_Float16)a.x; h[1] = (_Float16)a.y; h[2] = (_Float16)a.z; h[3] = (_Float16)a.w;
  h[4] = (_Float16)b.x; h[5] = (_Float16)b.y; h[6] = (_Float16)b.z; h[7] = (_Float16)b.w;
  return h;
}

// ---------------- prep: weights f32 -> f16 ----------------------------------
__global__ __launch_bounds__(256)
void fgrnn_prep(const float* __restrict__ W1, const float* __restrict__ U1,
                const float* __restrict__ W2, const float* __restrict__ U2,
                _Float16* __restrict__ wb) {
  const int q = blockIdx.x * 256 + threadIdx.x;
  const float* src;
  int rel;
  if (q < 65536) { src = W1; rel = q; }
  else if (q < 196608) { src = U1; rel = q - 65536; }
  else if (q < 327680) { src = W2; rel = q - 196608; }
  else { src = U2; rel = q - 327680; }
  const float4 v = reinterpret_cast<const float4*>(src)[rel];
  union { _Float16 h[4]; uint2 u; } cv;
  cv.h[0] = (_Float16)v.x; cv.h[1] = (_Float16)v.y;
  cv.h[2] = (_Float16)v.z; cv.h[3] = (_Float16)v.w;
  reinterpret_cast<uint2*>(wb)[q] = cv.u;
}

// ---------------- stage 1 body: BMxBN=(MI*32)x256, K=1024, 16 iters ---------
// 8 waves 2x4; wave tile (MI*16)x64 (acc[MI][4]). Double-buffered LDS; one raw
// barrier per iter (lgkmcnt(0) only -- vmcnt NOT drained, so tile t+2's global
// loads overlap two full iterations of compute).
template <int MI>  // 2 (BM=64) or 4 (BM=128)
__device__ __forceinline__ void s1_body(
    const float* __restrict__ A, const int KA, const int kbase,
    const _Float16* __restrict__ Bw, _Float16* __restrict__ rbuf,
    const int row0, const int colbase,
    _Float16* __restrict__ AsBase, _Float16* __restrict__ BsBase) {
  constexpr int APASS = MI / 2;           // A staging passes (1 or 2)
  constexpr int ASTRIDE = MI * 32 * 64;   // halves per As buffer
  constexpr int BSTRIDE = 256 * 64;

  const int tid = threadIdx.x;
  const int lane = tid & 63;
  const int w = tid >> 6;
  const int wr = w >> 2, wc = w & 3;
  const int sr = tid >> 3;        // 0..63
  const int sc = (tid & 7) * 8;

  f32x4 acc[MI][4];
#pragma unroll
  for (int i = 0; i < MI; ++i)
#pragma unroll
    for (int j = 0; j < 4; ++j) acc[i][j] = (f32x4){0.f, 0.f, 0.f, 0.f};

  // two named register sets (static indexing; rule: no runtime-indexed arrays)
  float4 raE[APASS][2], raO[APASS][2];
  half8 rbE[4], rbO[4];

  auto LOADG = [&](float4 (&ra)[APASS][2], half8 (&rb)[4], int it) {
    const int k0 = kbase + it * 64;
#pragma unroll
    for (int j = 0; j < APASS; ++j) {
      const float* s = A + (size_t)(row0 + j * 64 + sr) * KA + k0 + sc;
      ra[j][0] = *reinterpret_cast<const float4*>(s);
      ra[j][1] = *reinterpret_cast<const float4*>(s + 4);
    }
#pragma unroll
    for (int j = 0; j < 4; ++j)
      rb[j] = *reinterpret_cast<const half8*>(Bw + (size_t)(j * 64 + sr) * KA + k0 + sc);
  };
  auto STORE = [&](const float4 (&ra)[APASS][2], const half8 (&rb)[4],
                   _Float16* as, _Float16* bs) {
#pragma unroll
    for (int j = 0; j < APASS; ++j) {
      const int r = j * 64 + sr;
      *reinterpret_cast<half8*>(&as[r * 64 + (sc ^ ((r & 7) << 3))]) =
          cvt8(ra[j][0], ra[j][1]);
    }
#pragma unroll
    for (int j = 0; j < 4; ++j) {
      const int r = j * 64 + sr;
      *reinterpret_cast<half8*>(&bs[r * 64 + (sc ^ ((r & 7) << 3))]) = rb[j];
    }
  };
  auto COMPUTE = [&](const _Float16* as, const _Float16* bs) {
#pragma unroll
    for (int kk = 0; kk < 64; kk += 32) {
      half8 af[MI], bf[4];
#pragma unroll
      for (int mi = 0; mi < MI; ++mi) {
        const int r = wr * (MI * 16) + mi * 16 + (lane & 15);
        af[mi] = *reinterpret_cast<const half8*>(
            &as[r * 64 + ((kk + 8 * (lane >> 4)) ^ ((r & 7) << 3))]);
      }
#pragma unroll
      for (int ni = 0; ni < 4; ++ni) {
        const int r = wc * 64 + ni * 16 + (lane & 15);
        bf[ni] = *reinterpret_cast<const half8*>(
            &bs[r * 64 + ((kk + 8 * (lane >> 4)) ^ ((r & 7) << 3))]);
      }
#pragma unroll
      for (int mi = 0; mi < MI; ++mi)
#pragma unroll
        for (int ni = 0; ni < 4; ++ni)
          acc[mi][ni] =
              __builtin_amdgcn_mfma_f32_16x16x32_f16(af[mi], bf[ni], acc[mi][ni], 0, 0, 0);
    }
  };
  auto BAR = [&]() {
    asm volatile("s_waitcnt lgkmcnt(0)" ::: "memory");  // drain LDS writes only
    __builtin_amdgcn_s_barrier();                       // vmcnt stays in flight
    asm volatile("" ::: "memory");
  };

  _Float16* as0 = AsBase;
  _Float16* as1 = AsBase + ASTRIDE;
  _Float16* bs0 = BsBase;
  _Float16* bs1 = BsBase + BSTRIDE;

  LOADG(raE, rbE, 0);
  LOADG(raO, rbO, 1);                 // in flight across prologue barrier
  STORE(raE, rbE, as0, bs0);          // compiler: counted vmcnt (waits set E only)
  BAR();

#pragma unroll 1
  for (int it2 = 0; it2 < 16; it2 += 2) {
    // even iter: compute tile it2 (buf0); store tile it2+1; prefetch it2+2
    if (it2 + 2 < 16) LOADG(raE, rbE, it2 + 2);
    COMPUTE(as0, bs0);
    STORE(raO, rbO, as1, bs1);
    BAR();
    // odd iter: compute tile it2+1 (buf1); store tile it2+2; prefetch it2+3
    if (it2 + 3 < 16) LOADG(raO, rbO, it2 + 3);
    COMPUTE(as1, bs1);
    if (it2 + 2 < 16) STORE(raE, rbE, as0, bs0);
    BAR();
  }

  // D layout (16x16 family): row = 4*(lane>>4)+e, col = lane&15.
#pragma unroll
  for (int mi = 0; mi < MI; ++mi)
#pragma unroll
    for (int ni = 0; ni < 4; ++ni)
#pragma unroll
      for (int e = 0; e < 4; ++e) {
        const int row = row0 + wr * (MI * 16) + mi * 16 + 4 * (lane >> 4) + e;
        const int col = colbase + wc * 64 + ni * 16 + (lane & 15);
        rbuf[(size_t)row * RBLD + col] = (_Float16)acc[mi][ni][e];
      }
}

__global__ __launch_bounds__(512)
void fgrnn_stage1(const float* __restrict__ x, const float* __restrict__ h,
                  const _Float16* __restrict__ wb, _Float16* __restrict__ rbuf) {
  __shared__ _Float16 As[2 * 128 * 64];   // 32 KB (g0 uses half per buffer)
  __shared__ _Float16 Bs[2 * 256 * 64];   // 64 KB
  const int bid = blockIdx.x;
  if (bid < 128) {
    s1_body<2>(x, DIN, 0, wb + OFF_W1H, rbuf, bid * 64, 0, As, Bs);
  } else if (bid < 192) {
    s1_body<4>(h, DH, 0, wb + OFF_U1H, rbuf, (bid - 128) * 128, 256, As, Bs);
  } else {
    s1_body<4>(h, DH, 1024, wb + OFF_U1H, rbuf, (bid - 192) * 128, 512, As, Bs);
  }
}

// ---------------- stage 2: pre = [wx | uh0+uh1] @ [W2|U2]^T, K=512 ----------
// 2048 blocks x 256 threads. BM=64, BN=128, BK=64, 8 iters; 4 waves 2x2,
// wave tile 32x64 (acc[2][4]). uh panel add fused into A staging.
__global__ __launch_bounds__(256)
void fgrnn_stage2(const _Float16* __restrict__ rbuf, const _Float16* __restrict__ wb,
                  const float* __restrict__ state,
                  const float* __restrict__ bg, const float* __restrict__ bu,
                  const float* __restrict__ zeta, const float* __restrict__ nu,
                  float* __restrict__ out) {
  const int bid = blockIdx.x;
  const int L = (bid & 7) * 256 + (bid >> 3);   // XCD swizzle: mtile-banded
  const int mtile = L >> 4;   // 0..127
  const int ntile = L & 15;   // 0..15
  const int row0 = mtile * 64;
  const int col0 = ntile * 128;
  const _Float16* W2h = wb + OFF_W2H;
  const _Float16* U2h = wb + OFF_U2H;

  __shared__ _Float16 As[64 * 64];
  __shared__ _Float16 Bs[128 * 64];

  const int tid = threadIdx.x;
  const int lane = tid & 63;
  const int w = tid >> 6;
  const int wr = w >> 1, wc = w & 1;

  f32x4 acc[2][4];
#pragma unroll
  for (int i = 0; i < 2; ++i)
#pragma unroll
    for (int j = 0; j < 4; ++j) acc[i][j] = (f32x4){0.f, 0.f, 0.f, 0.f};

  const int sr = tid >> 3;      // 0..31
  const int sc = (tid & 7) * 8;

  half8 pa[2], pa2[2], pb[4];

  auto LOADG = [&](int it) {
    const int k0 = it * 64;
    const bool iswx = (k0 < 256);
#pragma unroll
    for (int j = 0; j < 2; ++j) {
      const _Float16* p = rbuf + (size_t)(row0 + j * 32 + sr) * RBLD + k0 + sc;
      pa[j] = *reinterpret_cast<const half8*>(p);
      if (!iswx) pa2[j] = *reinterpret_cast<const half8*>(p + 256);  // uh1 panel
    }
    const _Float16* Bh = iswx ? W2h : U2h;
    const int kb = k0 & 255;
#pragma unroll
    for (int j = 0; j < 4; ++j)
      pb[j] = *reinterpret_cast<const half8*>(Bh + (size_t)(col0 + j * 32 + sr) * RK + kb + sc);
  };
  auto STORE = [&](int it) {
    const int k0 = it * 64;
#pragma unroll
    for (int j = 0; j < 2; ++j) {
      half8 v = pa[j];
      if (k0 >= 256) v = v + pa2[j];   // uh = uh0 + uh1 (v_pk_add_f16)
      const int r = j * 32 + sr;
      *reinterpret_cast<half8*>(&As[r * 64 + (sc ^ ((r & 7) << 3))]) = v;
    }
#pragma unroll
    for (int j = 0; j < 4; ++j) {
      const int r = j * 32 + sr;
      *reinterpret_cast<half8*>(&Bs[r * 64 + (sc ^ ((r & 7) << 3))]) = pb[j];
    }
  };

  LOADG(0);
  STORE(0);
  __syncthreads();

  for (int it = 0; it < 8; ++it) {
    const bool more = (it + 1 < 8);
    if (more) LOADG(it + 1);
#pragma unroll
    for (int kk = 0; kk < 64; kk += 32) {
      half8 af[2], bf[4];
#pragma unroll
      for (int mi = 0; mi < 2; ++mi) {
        const int r = wr * 32 + mi * 16 + (lane & 15);
        af[mi] = *reinterpret_cast<const half8*>(
            &As[r * 64 + ((kk + 8 * (lane >> 4)) ^ ((r & 7) << 3))]);
      }
#pragma unroll
      for (int ni = 0; ni < 4; ++ni) {
        const int r = wc * 64 + ni * 16 + (lane & 15);
        bf[ni] = *reinterpret_cast<const half8*>(
            &Bs[r * 64 + ((kk + 8 * (lane >> 4)) ^ ((r & 7) << 3))]);
      }
#pragma unroll
      for (int mi = 0; mi < 2; ++mi)
#pragma unroll
        for (int ni = 0; ni < 4; ++ni)
          acc[mi][ni] =
              __builtin_amdgcn_mfma_f32_16x16x32_f16(af[mi], bf[ni], acc[mi][ni], 0, 0, 0);
    }
    if (more) {
      __syncthreads();
      STORE(it + 1);
    }
    __syncthreads();
  }

  // Fused epilogue (fast exp2/rcp; asymptotes correct)
  const float LOG2E = 1.44269504f;
  const float sz = __builtin_amdgcn_rcpf(1.f + __builtin_amdgcn_exp2f(-zeta[0] * LOG2E));
  const float sn = __builtin_amdgcn_rcpf(1.f + __builtin_amdgcn_exp2f(-nu[0] * LOG2E));
#pragma unroll
  for (int mi = 0; mi < 2; ++mi)
#pragma unroll
    for (int ni = 0; ni < 4; ++ni) {
      const int col = col0 + wc * 64 + ni * 16 + (lane & 15);
      const float bgc = bg[col];
      const float buc = bu[col];
#pragma unroll
      for (int e = 0; e < 4; ++e) {
        const int row = row0 + wr * 32 + mi * 16 + 4 * (lane >> 4) + e;
        const float pre = acc[mi][ni][e];
        const float zg =
            __builtin_amdgcn_rcpf(1.f + __builtin_amdgcn_exp2f(-(pre + bgc) * LOG2E));
        const float hc =
            1.f - 2.f * __builtin_amdgcn_rcpf(
                            1.f + __builtin_amdgcn_exp2f((pre + buc) * (2.f * LOG2E)));
        const float sv = state[(size_t)row * DH + col];
        out[(size_t)row * DH + col] = zg * sv + (sz * (1.f - zg) + sn) * hc;
      }
    }
}

extern "C" void kernel_launch(void* const* d_in, const int* in_sizes, int n_in,
                              void* d_out, int out_size, void* d_ws, size_t ws_size,
                              hipStream_t stream) {
  const float* input = (const float*)d_in[0];
  const float* state = (const float*)d_in[1];
  const float* W1 = (const float*)d_in[2];
  const float* W2 = (const float*)d_in[3];
  const float* U1 = (const float*)d_in[4];
  const float* U2 = (const float*)d_in[5];
  const float* bg = (const float*)d_in[6];
  const float* bu = (const float*)d_in[7];
  const float* zeta = (const float*)d_in[8];
  const float* nu = (const float*)d_in[9];
  float* out = (float*)d_out;

  _Float16* rbuf = (_Float16*)d_ws;                     // 8192*768*2 = 12.6 MB
  _Float16* wb = rbuf + (size_t)8192 * RBLD;            // +3.67 MB f16 weights

  fgrnn_prep<<<1792, 256, 0, stream>>>(W1, U1, W2, U2, wb);
  fgrnn_stage1<<<256, 512, 0, stream>>>(input, state, wb, rbuf);
  fgrnn_stage2<<<2048, 256, 0, stream>>>(rbuf, wb, state, bg, bu, zeta, nu, out);
}